// Round 1
// baseline (931.158 us; speedup 1.0000x reference)
//
#include <hip/hip_runtime.h>
#include <hip/hip_fp16.h>

// Problem constants (IndyLSTM: B=32, T=2048, I=H=512)
#define B_  32
#define T_  2048
#define H_  512
#define K_  512          // input size I (GEMM K)
#define N_  2048         // 4*H (GEMM N), column index n' = h*4 + g  (g: 0=f,1=i,2=o,3=c)

typedef __attribute__((ext_vector_type(8))) __bf16 bf16x8;
typedef __attribute__((ext_vector_type(4))) __bf16 bf16x4;
typedef __attribute__((ext_vector_type(4))) float  floatx4;

// ---------------- conversion kernels (split bf16: v = hi + lo, fp32-accurate) ----------------

__global__ void convert_x(const float* __restrict__ x,
                          __bf16* __restrict__ xh, __bf16* __restrict__ xl, int n4) {
    int i = blockIdx.x * blockDim.x + threadIdx.x;
    if (i < n4) {
        const float4 v = ((const float4*)x)[i];
        bf16x4 hi, lo;
        hi[0] = (__bf16)v.x; lo[0] = (__bf16)(v.x - (float)hi[0]);
        hi[1] = (__bf16)v.y; lo[1] = (__bf16)(v.y - (float)hi[1]);
        hi[2] = (__bf16)v.z; lo[2] = (__bf16)(v.z - (float)hi[2]);
        hi[3] = (__bf16)v.w; lo[3] = (__bf16)(v.w - (float)hi[3]);
        *(bf16x4*)(xh + 4 * (size_t)i) = hi;
        *(bf16x4*)(xl + 4 * (size_t)i) = lo;
    }
}

// Wt[n'][k] = W_g[k][h] with n' = h*4+g  (k-contiguous => "B^T" layout for GEMM)
__global__ void convert_w(const float* __restrict__ Wf, const float* __restrict__ Wi,
                          const float* __restrict__ Wo, const float* __restrict__ Wc,
                          __bf16* __restrict__ Wh, __bf16* __restrict__ Wl) {
    int o = blockIdx.x * blockDim.x + threadIdx.x;   // [0, N_*K_)
    int k = o & (K_ - 1);
    int n = o >> 9;          // n' in [0,2048)
    int g = n & 3, h = n >> 2;
    const float* W = (g == 0) ? Wf : (g == 1) ? Wi : (g == 2) ? Wo : Wc;
    float v = W[k * H_ + h];
    __bf16 hi = (__bf16)v;
    Wh[o] = hi;
    Wl[o] = (__bf16)(v - (float)hi);
}

// ---------------- split-bf16 MFMA GEMM ----------------
// C[m][n] = sum_k A[m][k]*Bt[n][k] with A ~ Ah+Al, Bt ~ Bh+Bl
// acc += Ah*Bh + Ah*Bl + Al*Bh   (fp32-accurate to ~2^-18 relative); C stored fp16
//
// Round-1 changes vs prior session:
//  (a) LDS double-buffer, prefetch next K-tile BEFORE computing current one
//      (single __syncthreads per iter; its vmcnt(0) drain lands AFTER ~460cy of MFMA)
//  (b) bank-conflict swizzle: chunk ^= (row>>1)&3, applied on the GLOBAL source
//      (LDS dest of global_load_lds must stay linear) and on the ds_read address.
#define BM 128
#define BN 128
#define BK 32
#define NIT (K_ / BK)     // 16

__device__ __forceinline__ void async_copy16(const __bf16* g, __bf16* l) {
    __builtin_amdgcn_global_load_lds(
        (const __attribute__((address_space(1))) void*)g,
        (__attribute__((address_space(3))) void*)l,
        16, 0, 0);
}

__global__ __launch_bounds__(256, 2)
void gemm_bt(const __bf16* __restrict__ Ah, const __bf16* __restrict__ Al,
             const __bf16* __restrict__ Bh, const __bf16* __restrict__ Bl,
             __half* __restrict__ C) {
    __shared__ __align__(16) __bf16 AsH[2][BM * BK];
    __shared__ __align__(16) __bf16 AsL[2][BM * BK];
    __shared__ __align__(16) __bf16 BsH[2][BN * BK];
    __shared__ __align__(16) __bf16 BsL[2][BN * BK];

    const int tid  = threadIdx.x;
    const int lane = tid & 63;
    const int wave = tid >> 6;

    const int ntiles = N_ / BN;                 // 16
    const int bm = blockIdx.x / ntiles;
    const int bn = blockIdx.x % ntiles;
    const int m0 = bm * BM, n0 = bn * BN;

    const int waveM = (wave & 1) * 64;
    const int waveN = (wave >> 1) * 64;
    const int lm = lane & 15;
    const int q  = lane >> 4;
    // read-side swizzle: element offset of this lane's 16B chunk within a row
    const int lks = ((q ^ ((lm >> 1) & 3)) * 8);

    floatx4 acc[4][4] = {};

    // staging: tile = 512 x 16B chunks; thread handles chunks tid and tid+256.
    // chunk c -> row c>>2, lds col-chunk c&3; source col-chunk is XOR-swizzled.
    const int r0  = tid >> 2;                                  // 0..63
    const int swc = ((tid & 3) ^ ((tid >> 3) & 3)) * 8;        // swizzled source col (elems)
    const size_t a_g0 = (size_t)(m0 + r0) * K_ + swc;
    const size_t a_g1 = (size_t)(m0 + r0 + 64) * K_ + swc;
    const size_t b_g0 = (size_t)(n0 + r0) * K_ + swc;
    const size_t b_g1 = (size_t)(n0 + r0 + 64) * K_ + swc;
    const int w512 = wave * 512;                // wave-uniform LDS base (1024B per wave)

#define STAGE(bi, kof)                                              \
    do {                                                            \
        async_copy16(Ah + a_g0 + (kof), &AsH[bi][w512]);            \
        async_copy16(Ah + a_g1 + (kof), &AsH[bi][2048 + w512]);     \
        async_copy16(Al + a_g0 + (kof), &AsL[bi][w512]);            \
        async_copy16(Al + a_g1 + (kof), &AsL[bi][2048 + w512]);     \
        async_copy16(Bh + b_g0 + (kof), &BsH[bi][w512]);            \
        async_copy16(Bh + b_g1 + (kof), &BsH[bi][2048 + w512]);     \
        async_copy16(Bl + b_g0 + (kof), &BsL[bi][w512]);            \
        async_copy16(Bl + b_g1 + (kof), &BsL[bi][2048 + w512]);     \
    } while (0)

    STAGE(0, 0);
    __syncthreads();                            // tile 0 resident (vmcnt drained)

    for (int it = 0; it < NIT; ++it) {
        const int bi = it & 1;
        if (it + 1 < NIT) STAGE(bi ^ 1, (it + 1) * BK);   // prefetch next tile (in flight)

        bf16x8 ah[4], al[4], bh[4], bl[4];
#pragma unroll
        for (int mi = 0; mi < 4; mi++) {
            ah[mi] = *(const bf16x8*)(&AsH[bi][(waveM + mi * 16 + lm) * BK + lks]);
            al[mi] = *(const bf16x8*)(&AsL[bi][(waveM + mi * 16 + lm) * BK + lks]);
        }
#pragma unroll
        for (int ni = 0; ni < 4; ni++) {
            bh[ni] = *(const bf16x8*)(&BsH[bi][(waveN + ni * 16 + lm) * BK + lks]);
            bl[ni] = *(const bf16x8*)(&BsL[bi][(waveN + ni * 16 + lm) * BK + lks]);
        }
#pragma unroll
        for (int mi = 0; mi < 4; mi++)
#pragma unroll
            for (int ni = 0; ni < 4; ni++) {
                acc[mi][ni] = __builtin_amdgcn_mfma_f32_16x16x32_bf16(
                    ah[mi], bh[ni], acc[mi][ni], 0, 0, 0);
                acc[mi][ni] = __builtin_amdgcn_mfma_f32_16x16x32_bf16(
                    ah[mi], bl[ni], acc[mi][ni], 0, 0, 0);
                acc[mi][ni] = __builtin_amdgcn_mfma_f32_16x16x32_bf16(
                    al[mi], bh[ni], acc[mi][ni], 0, 0, 0);
            }
        // drains vmcnt(0) (next tile now resident) + lgkmcnt + barrier:
        // safe to overwrite buffer bi on the next iteration.
        __syncthreads();
    }
#undef STAGE

    // epilogue: C/D layout col = lane&15, row = (lane>>4)*4 + r; store fp16
#pragma unroll
    for (int mi = 0; mi < 4; mi++) {
        const int m = m0 + waveM + mi * 16 + (lane >> 4) * 4;
#pragma unroll
        for (int ni = 0; ni < 4; ni++) {
            const int n = n0 + waveN + ni * 16 + lm;
#pragma unroll
            for (int r = 0; r < 4; r++)
                C[(size_t)(m + r) * N_ + n] = __float2half(acc[mi][ni][r]);
        }
    }
}

// ---------------- quad-cooperative recurrent scan ----------------
// 4 lanes per (b,j) chain, one gate per lane (g = lane&3: 0=f,1=i,2=o,3=z).
// Uniform per-lane math with folded constants:
//   sigmoid lanes: v = rcp(1 + 2^(mu*h + mq*q + c0)),            mu=-u*log2e
//   z lane:        v = 1 - 2*rcp(1 + 2^(mu*h + mq*q + c0)),      mu=+2u*log2e
// Gate values broadcast to all 4 lanes via DPP quad_perm (VALU-rate).

template<int CTRL>
__device__ __forceinline__ float qperm(float v) {
    return __builtin_bit_cast(float,
        __builtin_amdgcn_mov_dpp(__builtin_bit_cast(int, v), CTRL, 0xF, 0xF, true));
}

#define PF 16   // prefetch depth; over-prefetches harmlessly into adjacent ws region

__global__ __launch_bounds__(256)
void scan_kernel(const __half* __restrict__ pre,   // [B*T][2048] fp16, col = j*4+g
                 const float* __restrict__ uf_, const float* __restrict__ bf_,
                 const float* __restrict__ ui_, const float* __restrict__ bi_,
                 const float* __restrict__ uo_, const float* __restrict__ bo_,
                 const float* __restrict__ uc_, const float* __restrict__ bc_,
                 float* __restrict__ out) {
    const int tid   = blockIdx.x * 256 + threadIdx.x;
    const int g     = tid & 3;
    const int chain = tid >> 2;        // [0, 16384)
    const int j     = chain & 511;
    const int b     = chain >> 9;

    const float* up = (g == 0) ? uf_ : (g == 1) ? ui_ : (g == 2) ? uo_ : uc_;
    const float* bp = (g == 0) ? bf_ : (g == 1) ? bi_ : (g == 2) ? bo_ : bc_;
    const float u  = up[j];
    const float bb = bp[j];

    const float L2E = 1.44269504f;
    const bool  isz = (g == 3);
    const float mq  = isz ?  2.0f * L2E : -L2E;   // multiplies q (pre value)
    const float mu  = u * mq;                      // multiplies h
    const float c0  = bb * mq;                     // folded bias
    const float Av  = isz ? -2.0f : 1.0f;
    const float Bv  = isz ?  1.0f : 0.0f;
    const float K2  = 2.0f * L2E;                  // tanh(c) exponent scale

    const __half* p = pre + ((size_t)b * T_) * N_ + (size_t)j * 4 + g;
    float* o = out + ((size_t)b * T_) * H_ + j;

    float h = 0.0f, c = 0.0f;

    __half ring[PF];
#pragma unroll
    for (int i = 0; i < PF; i++)
        ring[i] = p[(size_t)i * N_];
    const __half* pl = p + (size_t)PF * N_;

#pragma unroll 16
    for (int t = 0; t < T_; ++t) {
        float qf = (float)ring[t & (PF - 1)];
        ring[t & (PF - 1)] = *pl;                 // over-prefetch past end: lands in ws, unused
        pl += (size_t)N_;

        float a    = __builtin_fmaf(qf, mq, c0);          // off h-chain
        float e    = __builtin_amdgcn_exp2f(__builtin_fmaf(h, mu, a));
        float s    = __builtin_amdgcn_rcpf(1.0f + e);
        float v    = __builtin_fmaf(Av, s, Bv);           // f/i/o sigmoid or z tanh

        float f  = qperm<0x00>(v);    // quad_perm [0,0,0,0]
        float ii = qperm<0x55>(v);    // [1,1,1,1]
        float oo = qperm<0xAA>(v);    // [2,2,2,2]
        float z  = qperm<0xFF>(v);    // [3,3,3,3]

        c = __builtin_fmaf(f, c, ii * z);

        float e2 = __builtin_amdgcn_exp2f(c * K2);
        float tc = __builtin_fmaf(-2.0f, __builtin_amdgcn_rcpf(1.0f + e2), 1.0f);
        h = oo * tc;

        if (g == 0)
            o[(size_t)t * H_] = h;
    }
}

// ---------------- launch ----------------

extern "C" void kernel_launch(void* const* d_in, const int* in_sizes, int n_in,
                              void* d_out, int out_size, void* d_ws, size_t ws_size,
                              hipStream_t stream) {
    const float* x  = (const float*)d_in[0];
    const float* Wf = (const float*)d_in[1];
    const float* uf = (const float*)d_in[2];
    const float* bf = (const float*)d_in[3];
    const float* Wi = (const float*)d_in[4];
    const float* ui = (const float*)d_in[5];
    const float* bi = (const float*)d_in[6];
    const float* Wo = (const float*)d_in[7];
    const float* uo = (const float*)d_in[8];
    const float* bo = (const float*)d_in[9];
    const float* Wc = (const float*)d_in[10];
    const float* uc = (const float*)d_in[11];
    const float* bc = (const float*)d_in[12];
    float* out = (float*)d_out;

    // ws layout: pre fp16 (256 MiB) | xh (64) | xl (64) | Wh (2) | Wl (2)  = 388 MiB
    const size_t preB = (size_t)B_ * T_ * N_ * 2;
    const size_t xB   = (size_t)B_ * T_ * K_ * 2;
    const size_t wB   = (size_t)N_ * K_ * 2;

    __half* pre = (__half*)d_ws;
    __bf16* xh  = (__bf16*)((char*)d_ws + preB);
    __bf16* xl  = (__bf16*)((char*)d_ws + preB + xB);
    __bf16* Wh  = (__bf16*)((char*)d_ws + preB + 2 * xB);
    __bf16* Wl  = (__bf16*)((char*)d_ws + preB + 2 * xB + wB);
    (void)ws_size; (void)wB;

    convert_x<<<(B_ * T_ * K_ / 4 + 255) / 256, 256, 0, stream>>>(x, xh, xl, B_ * T_ * K_ / 4);
    convert_w<<<(N_ * K_) / 256, 256, 0, stream>>>(Wf, Wi, Wo, Wc, Wh, Wl);

    // h_t, c_t outputs are zeros
    hipMemsetAsync((char*)d_out + (size_t)B_ * T_ * H_ * 4, 0,
                   2 * (size_t)B_ * H_ * 4, stream);

    const int M = B_ * T_;                                   // 65536
    gemm_bt<<<dim3((M / BM) * (N_ / BN)), 256, 0, stream>>>(xh, xl, Wh, Wl, pre);

    scan_kernel<<<dim3(B_ * H_ * 4 / 256), 256, 0, stream>>>(
        pre, uf, bf, ui, bi, uo, bo, uc, bc, out);
}

// Round 2
// 803.481 us; speedup vs baseline: 1.1589x; 1.1589x over previous
//
#include <hip/hip_runtime.h>
#include <hip/hip_fp16.h>

// Problem constants (IndyLSTM: B=32, T=2048, I=H=512)
#define B_  32
#define T_  2048
#define H_  512
#define K_  512          // input size I (GEMM K)
#define N_  2048         // 4*H (GEMM N), column index n' = h*4 + g  (g: 0=f,1=i,2=o,3=c)

typedef __attribute__((ext_vector_type(8))) __bf16 bf16x8;
typedef __attribute__((ext_vector_type(4))) __bf16 bf16x4;
typedef __attribute__((ext_vector_type(4))) float  floatx4;

// ---------------- conversion kernels (split bf16: v = hi + lo, fp32-accurate) ----------------

__global__ void convert_x(const float* __restrict__ x,
                          __bf16* __restrict__ xh, __bf16* __restrict__ xl, int n4) {
    int i = blockIdx.x * blockDim.x + threadIdx.x;
    if (i < n4) {
        const float4 v = ((const float4*)x)[i];
        bf16x4 hi, lo;
        hi[0] = (__bf16)v.x; lo[0] = (__bf16)(v.x - (float)hi[0]);
        hi[1] = (__bf16)v.y; lo[1] = (__bf16)(v.y - (float)hi[1]);
        hi[2] = (__bf16)v.z; lo[2] = (__bf16)(v.z - (float)hi[2]);
        hi[3] = (__bf16)v.w; lo[3] = (__bf16)(v.w - (float)hi[3]);
        *(bf16x4*)(xh + 4 * (size_t)i) = hi;
        *(bf16x4*)(xl + 4 * (size_t)i) = lo;
    }
}

// Wt[n'][k] = W_g[k][h] with n' = h*4+g  (k-contiguous => "B^T" layout for GEMM)
__global__ void convert_w(const float* __restrict__ Wf, const float* __restrict__ Wi,
                          const float* __restrict__ Wo, const float* __restrict__ Wc,
                          __bf16* __restrict__ Wh, __bf16* __restrict__ Wl) {
    int o = blockIdx.x * blockDim.x + threadIdx.x;   // [0, N_*K_)
    int k = o & (K_ - 1);
    int n = o >> 9;          // n' in [0,2048)
    int g = n & 3, h = n >> 2;
    const float* W = (g == 0) ? Wf : (g == 1) ? Wi : (g == 2) ? Wo : Wc;
    float v = W[k * H_ + h];
    __bf16 hi = (__bf16)v;
    Wh[o] = hi;
    Wl[o] = (__bf16)(v - (float)hi);
}

// ---------------- split-bf16 MFMA GEMM ----------------
// C[m][n] = sum_k A[m][k]*Bt[n][k] with A ~ Ah+Al, Bt ~ Bh+Bl
// acc += Ah*Bh + Ah*Bl + Al*Bh   (fp32-accurate to ~2^-18 relative); C stored fp16
//
// Round-2: single-buffered (round-0 structure, 32 KB LDS -> ~2.7 blocks/CU implicit
// overlap; explicit dbuf regressed per R1 = m132 occupancy loss) + the R1-verified
// bank-conflict swizzle (conflicts 3.35e7 -> 0): chunk ^= (row>>1)&3 applied on the
// GLOBAL source (LDS dest of global_load_lds must stay linear) and on the ds_read.
#define BM 128
#define BN 128
#define BK 32

__device__ __forceinline__ void async_copy16(const __bf16* g, __bf16* l) {
    __builtin_amdgcn_global_load_lds(
        (const __attribute__((address_space(1))) void*)g,
        (__attribute__((address_space(3))) void*)l,
        16, 0, 0);
}

__global__ __launch_bounds__(256, 2)
void gemm_bt(const __bf16* __restrict__ Ah, const __bf16* __restrict__ Al,
             const __bf16* __restrict__ Bh, const __bf16* __restrict__ Bl,
             __half* __restrict__ C) {
    __shared__ __align__(16) __bf16 AsH[BM * BK];
    __shared__ __align__(16) __bf16 AsL[BM * BK];
    __shared__ __align__(16) __bf16 BsH[BN * BK];
    __shared__ __align__(16) __bf16 BsL[BN * BK];

    const int tid  = threadIdx.x;
    const int lane = tid & 63;
    const int wave = tid >> 6;

    const int ntiles = N_ / BN;                 // 16
    const int bm = blockIdx.x / ntiles;
    const int bn = blockIdx.x % ntiles;
    const int m0 = bm * BM, n0 = bn * BN;

    const int waveM = (wave & 1) * 64;
    const int waveN = (wave >> 1) * 64;
    const int lm = lane & 15;
    const int q  = lane >> 4;
    // read-side swizzle: chunk q -> q ^ ((row>>1)&3); row = ...+lm so only lm matters
    const int lks = (q ^ ((lm >> 1) & 3)) * 8;

    floatx4 acc[4][4] = {};

    // staging: tile = 512 x 16B chunks; thread handles chunks tid and tid+256.
    // chunk c -> row c>>2, lds col-chunk c&3; SOURCE col-chunk is XOR-swizzled
    // (same swizzle valid for rows r and r+64 since (+64)>>1 = +32 == 0 mod 4).
    const int r0  = tid >> 2;                                  // 0..63
    const int swc = ((tid & 3) ^ ((tid >> 3) & 3)) * 8;        // swizzled source col (elems)
    const size_t a_g0 = (size_t)(m0 + r0) * K_ + swc;
    const size_t a_g1 = (size_t)(m0 + r0 + 64) * K_ + swc;
    const size_t b_g0 = (size_t)(n0 + r0) * K_ + swc;
    const size_t b_g1 = (size_t)(n0 + r0 + 64) * K_ + swc;
    const int w512 = wave * 512;                // wave-uniform LDS base (1024B per wave)

    for (int k0 = 0; k0 < K_; k0 += BK) {
        async_copy16(Ah + a_g0 + k0, AsH + w512);
        async_copy16(Ah + a_g1 + k0, AsH + 2048 + w512);
        async_copy16(Al + a_g0 + k0, AsL + w512);
        async_copy16(Al + a_g1 + k0, AsL + 2048 + w512);
        async_copy16(Bh + b_g0 + k0, BsH + w512);
        async_copy16(Bh + b_g1 + k0, BsH + 2048 + w512);
        async_copy16(Bl + b_g0 + k0, BsL + w512);
        async_copy16(Bl + b_g1 + k0, BsL + 2048 + w512);
        __syncthreads();

        bf16x8 ah[4], al[4], bh[4], bl[4];
#pragma unroll
        for (int mi = 0; mi < 4; mi++) {
            ah[mi] = *(const bf16x8*)(AsH + (waveM + mi * 16 + lm) * BK + lks);
            al[mi] = *(const bf16x8*)(AsL + (waveM + mi * 16 + lm) * BK + lks);
        }
#pragma unroll
        for (int ni = 0; ni < 4; ni++) {
            bh[ni] = *(const bf16x8*)(BsH + (waveN + ni * 16 + lm) * BK + lks);
            bl[ni] = *(const bf16x8*)(BsL + (waveN + ni * 16 + lm) * BK + lks);
        }
#pragma unroll
        for (int mi = 0; mi < 4; mi++)
#pragma unroll
            for (int ni = 0; ni < 4; ni++) {
                acc[mi][ni] = __builtin_amdgcn_mfma_f32_16x16x32_bf16(
                    ah[mi], bh[ni], acc[mi][ni], 0, 0, 0);
                acc[mi][ni] = __builtin_amdgcn_mfma_f32_16x16x32_bf16(
                    ah[mi], bl[ni], acc[mi][ni], 0, 0, 0);
                acc[mi][ni] = __builtin_amdgcn_mfma_f32_16x16x32_bf16(
                    al[mi], bh[ni], acc[mi][ni], 0, 0, 0);
            }
        __syncthreads();
    }

    // epilogue: C/D layout col = lane&15, row = (lane>>4)*4 + r; store fp16
#pragma unroll
    for (int mi = 0; mi < 4; mi++) {
        const int m = m0 + waveM + mi * 16 + (lane >> 4) * 4;
#pragma unroll
        for (int ni = 0; ni < 4; ni++) {
            const int n = n0 + waveN + ni * 16 + lm;
#pragma unroll
            for (int r = 0; r < 4; r++)
                C[(size_t)(m + r) * N_ + n] = __float2half(acc[mi][ni][r]);
        }
    }
}

// ---------------- quad-cooperative recurrent scan ----------------
// 4 lanes per (b,j) chain, one gate per lane (g = lane&3: 0=f,1=i,2=o,3=z).
// Uniform per-lane math with folded constants:
//   sigmoid lanes: v = rcp(1 + 2^(mu*h + mq*q + c0)),            mu=-u*log2e
//   z lane:        v = 1 - 2*rcp(1 + 2^(mu*h + mq*q + c0)),      mu=+2u*log2e
// Gate values broadcast to all 4 lanes via DPP quad_perm (VALU-rate).
//
// Round-2: PF 16 -> 32 (double in-flight loads; scan is 1 wave/SIMD so the ring
// depth is the only MLP lever; ~16 extra VGPRs, no occupancy consequence).

template<int CTRL>
__device__ __forceinline__ float qperm(float v) {
    return __builtin_bit_cast(float,
        __builtin_amdgcn_mov_dpp(__builtin_bit_cast(int, v), CTRL, 0xF, 0xF, true));
}

#define PF 32   // prefetch depth; over-prefetches harmlessly into adjacent ws region

__global__ __launch_bounds__(256)
void scan_kernel(const __half* __restrict__ pre,   // [B*T][2048] fp16, col = j*4+g
                 const float* __restrict__ uf_, const float* __restrict__ bf_,
                 const float* __restrict__ ui_, const float* __restrict__ bi_,
                 const float* __restrict__ uo_, const float* __restrict__ bo_,
                 const float* __restrict__ uc_, const float* __restrict__ bc_,
                 float* __restrict__ out) {
    const int tid   = blockIdx.x * 256 + threadIdx.x;
    const int g     = tid & 3;
    const int chain = tid >> 2;        // [0, 16384)
    const int j     = chain & 511;
    const int b     = chain >> 9;

    const float* up = (g == 0) ? uf_ : (g == 1) ? ui_ : (g == 2) ? uo_ : uc_;
    const float* bp = (g == 0) ? bf_ : (g == 1) ? bi_ : (g == 2) ? bo_ : bc_;
    const float u  = up[j];
    const float bb = bp[j];

    const float L2E = 1.44269504f;
    const bool  isz = (g == 3);
    const float mq  = isz ?  2.0f * L2E : -L2E;   // multiplies q (pre value)
    const float mu  = u * mq;                      // multiplies h
    const float c0  = bb * mq;                     // folded bias
    const float Av  = isz ? -2.0f : 1.0f;
    const float Bv  = isz ?  1.0f : 0.0f;
    const float K2  = 2.0f * L2E;                  // tanh(c) exponent scale

    const __half* p = pre + ((size_t)b * T_) * N_ + (size_t)j * 4 + g;
    float* o = out + ((size_t)b * T_) * H_ + j;

    float h = 0.0f, c = 0.0f;

    __half ring[PF];
#pragma unroll
    for (int i = 0; i < PF; i++)
        ring[i] = p[(size_t)i * N_];
    const __half* pl = p + (size_t)PF * N_;

#pragma unroll 32
    for (int t = 0; t < T_; ++t) {
        float qf = (float)ring[t & (PF - 1)];
        ring[t & (PF - 1)] = *pl;                 // over-prefetch past end: lands in ws, unused
        pl += (size_t)N_;

        float a    = __builtin_fmaf(qf, mq, c0);          // off h-chain
        float e    = __builtin_amdgcn_exp2f(__builtin_fmaf(h, mu, a));
        float s    = __builtin_amdgcn_rcpf(1.0f + e);
        float v    = __builtin_fmaf(Av, s, Bv);           // f/i/o sigmoid or z tanh

        float f  = qperm<0x00>(v);    // quad_perm [0,0,0,0]
        float ii = qperm<0x55>(v);    // [1,1,1,1]
        float oo = qperm<0xAA>(v);    // [2,2,2,2]
        float z  = qperm<0xFF>(v);    // [3,3,3,3]

        c = __builtin_fmaf(f, c, ii * z);

        float e2 = __builtin_amdgcn_exp2f(c * K2);
        float tc = __builtin_fmaf(-2.0f, __builtin_amdgcn_rcpf(1.0f + e2), 1.0f);
        h = oo * tc;

        if (g == 0)
            o[(size_t)t * H_] = h;
    }
}

// ---------------- launch ----------------

extern "C" void kernel_launch(void* const* d_in, const int* in_sizes, int n_in,
                              void* d_out, int out_size, void* d_ws, size_t ws_size,
                              hipStream_t stream) {
    const float* x  = (const float*)d_in[0];
    const float* Wf = (const float*)d_in[1];
    const float* uf = (const float*)d_in[2];
    const float* bf = (const float*)d_in[3];
    const float* Wi = (const float*)d_in[4];
    const float* ui = (const float*)d_in[5];
    const float* bi = (const float*)d_in[6];
    const float* Wo = (const float*)d_in[7];
    const float* uo = (const float*)d_in[8];
    const float* bo = (const float*)d_in[9];
    const float* Wc = (const float*)d_in[10];
    const float* uc = (const float*)d_in[11];
    const float* bc = (const float*)d_in[12];
    float* out = (float*)d_out;

    // ws layout: pre fp16 (256 MiB) | xh (64) | xl (64) | Wh (2) | Wl (2)  = 388 MiB
    const size_t preB = (size_t)B_ * T_ * N_ * 2;
    const size_t xB   = (size_t)B_ * T_ * K_ * 2;
    const size_t wB   = (size_t)N_ * K_ * 2;

    __half* pre = (__half*)d_ws;
    __bf16* xh  = (__bf16*)((char*)d_ws + preB);
    __bf16* xl  = (__bf16*)((char*)d_ws + preB + xB);
    __bf16* Wh  = (__bf16*)((char*)d_ws + preB + 2 * xB);
    __bf16* Wl  = (__bf16*)((char*)d_ws + preB + 2 * xB + wB);
    (void)ws_size; (void)wB;

    convert_x<<<(B_ * T_ * K_ / 4 + 255) / 256, 256, 0, stream>>>(x, xh, xl, B_ * T_ * K_ / 4);
    convert_w<<<(N_ * K_) / 256, 256, 0, stream>>>(Wf, Wi, Wo, Wc, Wh, Wl);

    // h_t, c_t outputs are zeros
    hipMemsetAsync((char*)d_out + (size_t)B_ * T_ * H_ * 4, 0,
                   2 * (size_t)B_ * H_ * 4, stream);

    const int M = B_ * T_;                                   // 65536
    gemm_bt<<<dim3((M / BM) * (N_ / BN)), 256, 0, stream>>>(xh, xl, Wh, Wl, pre);

    scan_kernel<<<dim3(B_ * H_ * 4 / 256), 256, 0, stream>>>(
        pre, uf, bf, ui, bi, uo, bo, uc, bc, out);
}